// Round 1
// baseline (203.703 us; speedup 1.0000x reference)
//
#include <hip/hip_runtime.h>
#include <hip/hip_bf16.h>

#define DP     257
#define NP     2049
#define NSEQ   2048
#define NB     16
#define KLD    288         // pitch for small matrices (shorts)
#define HROWS  320         // padded rows for Hb
#define TPITCH 320         // Hbt pitch in shorts: 640 B = 5 full 128B lines
#define TROWS  2176        // padded t rows for Hbt (17*128)
#define KPAD   40          // LDS row pitch (shorts)

typedef __attribute__((ext_vector_type(8))) short bf16x8;
typedef __attribute__((ext_vector_type(4))) short bf16x4;
typedef __attribute__((ext_vector_type(4))) float f32x4;

// ---------------------------------------------------------------------------
// Convert H -> Hb (row-major bf16, 320 x 2048, = masked H-hat)
//           -> Hbt (transposed bf16, 2176 x 320-pitch, zero-padded)
// ---------------------------------------------------------------------------
__global__ __launch_bounds__(256) void conv_h(const float* __restrict__ H,
                                              __hip_bfloat16* __restrict__ Hb,
                                              __hip_bfloat16* __restrict__ Hbt) {
    const int b  = blockIdx.z;
    const int t0 = blockIdx.x * 64;
    const int e0 = blockIdx.y * 64;
    const float* __restrict__ Hs = H + (size_t)b * DP * NP;
    __hip_bfloat16* __restrict__ Hbb  = Hb  + (size_t)b * HROWS * 2048;
    __hip_bfloat16* __restrict__ Hbtb = Hbt + (size_t)b * TROWS * TPITCH;

    __shared__ float tile[64][65];

    const int tl = threadIdx.x & 63;
    const int er = threadIdx.x >> 6;
#pragma unroll
    for (int r = 0; r < 16; ++r) {
        const int el = er + r * 4;        // 0..63
        const int ge = e0 + el;
        const int gt = t0 + tl;
        float v = 0.f;
        if (ge < DP && gt < NP) v = Hs[(size_t)ge * NP + gt];
        tile[el][tl] = v;
        if (ge < HROWS && gt < 2048) Hbb[(size_t)ge * 2048 + gt] = __float2bfloat16(v);
    }
    __syncthreads();
#pragma unroll
    for (int r = 0; r < 16; ++r) {
        const int ttl = er + r * 4;       // t-local
        const int gt = t0 + ttl;
        const int ge = e0 + tl;           // e-local = lane -> contiguous writes
        if (gt < TROWS && ge < TPITCH) {
            const float v = (ge < KLD) ? tile[tl][ttl] : 0.f;
            Hbtb[(size_t)gt * TPITCH + ge] = __float2bfloat16(v);
        }
    }
}

// ---------------------------------------------------------------------------
// Pb[m][k] = P[m][k] (bf16, zero-padded to 288x288); Qt[n][k] = Q[k][n]
// ---------------------------------------------------------------------------
__global__ __launch_bounds__(256) void conv_pq(const float* __restrict__ P,
                                               const float* __restrict__ Q,
                                               __hip_bfloat16* __restrict__ Pb,
                                               __hip_bfloat16* __restrict__ Qt) {
    const int c0 = blockIdx.x * 64;
    const int r0 = blockIdx.y * 64;
    const int tl = threadIdx.x & 63;
    const int rr = threadIdx.x >> 6;
    __shared__ float tile[64][65];

    if (blockIdx.z == 0) {
#pragma unroll
        for (int r = 0; r < 16; ++r) {
            const int m = r0 + rr + r * 4;
            const int k = c0 + tl;
            float v = (m < DP && k < DP) ? P[m * DP + k] : 0.f;
            if (m < KLD && k < KLD) Pb[m * KLD + k] = __float2bfloat16(v);
        }
    } else {
#pragma unroll
        for (int r = 0; r < 16; ++r) {
            const int k = r0 + rr + r * 4;
            const int n = c0 + tl;
            float v = (k < DP && n < DP) ? Q[k * DP + n] : 0.f;
            tile[k - r0][n - c0] = v;
        }
        __syncthreads();
#pragma unroll
        for (int r = 0; r < 16; ++r) {
            const int k = r0 + tl;
            const int n = c0 + rr + r * 4;
            if (n < KLD && k < KLD) Qt[n * KLD + k] = __float2bfloat16(tile[tl][n - c0]);
        }
    }
}

// ---------------------------------------------------------------------------
// G[b] = Hb[b] @ Hb[b]^T, staged 64x64 tiles, 512 threads, split-K x2.
// (unchanged)
// ---------------------------------------------------------------------------
__global__ __launch_bounds__(512, 4) void gram_staged(const __hip_bfloat16* __restrict__ Hb,
                                                      __hip_bfloat16* __restrict__ G) {
    const int b  = blockIdx.y;
    const int tm = blockIdx.x / 5;
    const int tn = blockIdx.x % 5;
    const int m0 = tm * 64, n0 = tn * 64;
    const int tid = threadIdx.x;
    const int wave = tid >> 6, lane = tid & 63;
    const int lrow = lane & 15, kq = (lane >> 4) * 8;
    const int hw = wave >> 2;            // compute half
    const int q  = wave & 3;             // quadrant
    const int mh = (q & 1) * 32, nh = (q >> 1) * 32;
    const int hs = tid >> 8;             // staging half
    const int t2 = tid & 255;
    const int sr = t2 >> 2;              // 0..63
    const int sc = (t2 & 3) * 8;         // 0,8,16,24

    __shared__ __align__(16) char smem[2 * 2 * 2 * 64 * KPAD * 2];  // 40960 B
    short* As = (short*)smem;                    // [buf][h][64][KPAD]
    short* Bs = (short*)(smem + 2 * 2 * 64 * KPAD * 2);
    float* red = (float*)smem;                   // [8][32][32] (reused after loop)

    const short* __restrict__ base = (const short*)(Hb + (size_t)b * HROWS * 2048);

    auto aoff = [&](int buf, int h, int r) { return ((buf * 2 + h) * 64 + r) * KPAD; };

    f32x4 acc[2][2] = {};

    {
        const int kb = hs * 1024;
        *(bf16x8*)&As[aoff(0, hs, sr) + sc] = *(const bf16x8*)(base + (size_t)(m0 + sr) * 2048 + kb + sc);
        *(bf16x8*)&Bs[aoff(0, hs, sr) + sc] = *(const bf16x8*)(base + (size_t)(n0 + sr) * 2048 + kb + sc);
    }
    __syncthreads();

    for (int kt = 0; kt < 32; ++kt) {
        const int cur = kt & 1, nxt = cur ^ 1;
        if (kt + 1 < 32) {
            const int kb = hs * 1024 + (kt + 1) * 32;
            *(bf16x8*)&As[aoff(nxt, hs, sr) + sc] = *(const bf16x8*)(base + (size_t)(m0 + sr) * 2048 + kb + sc);
            *(bf16x8*)&Bs[aoff(nxt, hs, sr) + sc] = *(const bf16x8*)(base + (size_t)(n0 + sr) * 2048 + kb + sc);
        }
        bf16x8 a0 = *(const bf16x8*)&As[aoff(cur, hw, mh + lrow) + kq];
        bf16x8 a1 = *(const bf16x8*)&As[aoff(cur, hw, mh + 16 + lrow) + kq];
        bf16x8 b0 = *(const bf16x8*)&Bs[aoff(cur, hw, nh + lrow) + kq];
        bf16x8 b1 = *(const bf16x8*)&Bs[aoff(cur, hw, nh + 16 + lrow) + kq];
        acc[0][0] = __builtin_amdgcn_mfma_f32_16x16x32_bf16(a0, b0, acc[0][0], 0, 0, 0);
        acc[0][1] = __builtin_amdgcn_mfma_f32_16x16x32_bf16(a0, b1, acc[0][1], 0, 0, 0);
        acc[1][0] = __builtin_amdgcn_mfma_f32_16x16x32_bf16(a1, b0, acc[1][0], 0, 0, 0);
        acc[1][1] = __builtin_amdgcn_mfma_f32_16x16x32_bf16(a1, b1, acc[1][1], 0, 0, 0);
        __syncthreads();
    }

    const int ccol  = lane & 15;
    const int crow0 = (lane >> 4) * 4;
#pragma unroll
    for (int i = 0; i < 2; ++i)
#pragma unroll
        for (int j = 0; j < 2; ++j)
#pragma unroll
            for (int r = 0; r < 4; ++r)
                red[((wave * 32) + i * 16 + crow0 + r) * 32 + j * 16 + ccol] = acc[i][j][r];
    __syncthreads();

    const int q2  = tid >> 7;
    const int t7  = tid & 127;
    const int row = t7 >> 2;
    const int c8  = (t7 & 3) * 8;
    const int gm = m0 + (q2 & 1) * 32 + row;
    const int gn = n0 + (q2 >> 1) * 32 + c8;
    if (gm < KLD && gn < KLD) {
        __hip_bfloat16 o[8];
#pragma unroll
        for (int t = 0; t < 8; ++t) {
            const float v = red[((q2 * 32) + row) * 32 + c8 + t] +
                            red[(((q2 + 4) * 32) + row) * 32 + c8 + t];
            o[t] = __float2bfloat16((gm < DP && (gn + t) < DP) ? v : 0.f);
        }
        __hip_bfloat16* __restrict__ Gb = G + (size_t)b * KLD * KLD;
        *(bf16x8*)&Gb[gm * KLD + gn] = *(const bf16x8*)o;
    }
}

// ---------------------------------------------------------------------------
// C[b][m][n] = sum_k A[m][k] * B[n][k]  (K=288, ld=288), split-K x4.
// (unchanged)
// ---------------------------------------------------------------------------
__global__ __launch_bounds__(256) void mm_sk4(const __hip_bfloat16* __restrict__ A,
                                              const __hip_bfloat16* __restrict__ B,
                                              __hip_bfloat16* __restrict__ C,
                                              int strideA, int strideB) {
    const int b  = blockIdx.y;
    const int tm = blockIdx.x / 9;
    const int tn = blockIdx.x % 9;
    const int s    = threadIdx.x >> 6;
    const int lane = threadIdx.x & 63;
    const int lrow = lane & 15;
    const int koff = (lane >> 4) * 8;
    const short* __restrict__ Ab = (const short*)(A + (size_t)b * strideA);
    const short* __restrict__ Bb = (const short*)(B + (size_t)b * strideB);
    const int m0 = tm * 32, n0 = tn * 32;

    __shared__ float red[4][32][32];

    f32x4 acc[2][2] = {};
    for (int kt = s; kt < 9; kt += 4) {
        const int k0 = kt * 32;
        bf16x8 a0 = *(const bf16x8*)(Ab + (m0 + lrow)      * KLD + k0 + koff);
        bf16x8 a1 = *(const bf16x8*)(Ab + (m0 + 16 + lrow) * KLD + k0 + koff);
        bf16x8 c0 = *(const bf16x8*)(Bb + (n0 + lrow)      * KLD + k0 + koff);
        bf16x8 c1 = *(const bf16x8*)(Bb + (n0 + 16 + lrow) * KLD + k0 + koff);
        acc[0][0] = __builtin_amdgcn_mfma_f32_16x16x32_bf16(a0, c0, acc[0][0], 0, 0, 0);
        acc[0][1] = __builtin_amdgcn_mfma_f32_16x16x32_bf16(a0, c1, acc[0][1], 0, 0, 0);
        acc[1][0] = __builtin_amdgcn_mfma_f32_16x16x32_bf16(a1, c0, acc[1][0], 0, 0, 0);
        acc[1][1] = __builtin_amdgcn_mfma_f32_16x16x32_bf16(a1, c1, acc[1][1], 0, 0, 0);
    }

    const int ccol  = lane & 15;
    const int crow0 = (lane >> 4) * 4;
#pragma unroll
    for (int i = 0; i < 2; ++i)
#pragma unroll
        for (int j = 0; j < 2; ++j)
#pragma unroll
            for (int r = 0; r < 4; ++r)
                red[s][i * 16 + crow0 + r][j * 16 + ccol] = acc[i][j][r];
    __syncthreads();

    const int row = threadIdx.x >> 3;
    const int c4  = (threadIdx.x & 7) * 4;
    float4 v0 = *(const float4*)&red[0][row][c4];
    float4 v1 = *(const float4*)&red[1][row][c4];
    float4 v2 = *(const float4*)&red[2][row][c4];
    float4 v3 = *(const float4*)&red[3][row][c4];
    float sum[4] = {v0.x + v1.x + v2.x + v3.x,
                    v0.y + v1.y + v2.y + v3.y,
                    v0.z + v1.z + v2.z + v3.z,
                    v0.w + v1.w + v2.w + v3.w};
    const int gm = m0 + row;
    const int gn = n0 + c4;
    __hip_bfloat16 o[4];
#pragma unroll
    for (int t = 0; t < 4; ++t) {
        const float v = (gm < DP && (gn + t) < DP) ? sum[t] : 0.f;
        o[t] = __float2bfloat16(v);
    }
    __hip_bfloat16* __restrict__ Cb = C + (size_t)b * KLD * KLD;
    *(bf16x4*)&Cb[gm * KLD + gn] = *(const bf16x4*)o;
}

// ---------------------------------------------------------------------------
// out[b][d][t] = H[b][d][t] + (1/n) * sum_e Kb[d][e] * Hbt[t][e]
//
// v3: NO main-loop LDS, NO main-loop barriers. Per-block working set
// (Kb rows 37 KB, Hbt tile 74 KB) is L2-resident, so MFMA fragments are
// read DIRECTLY from global/L2 (each frag read = 16 rows x 64 B fully-used
// lines) with a rolling 1-chunk register prefetch. LDS (8.4 KB) used only
// for the epilogue re-layout; epilogue RMW is lane-contiguous dword with a
// block-uniform fast path (H pitch 2049 floats is odd -> no float4).
// ---------------------------------------------------------------------------
__global__ __launch_bounds__(256, 4) void attn_v3(const __hip_bfloat16* __restrict__ Kb,
                                                  const __hip_bfloat16* __restrict__ Hbt,
                                                  const float* __restrict__ H,
                                                  float* __restrict__ Out) {
    const int b  = blockIdx.z;
    const int d0 = blockIdx.y * 64;
    const int t0 = blockIdx.x * 128;
    const int tid = threadIdx.x;
    const int wave = tid >> 6, lane = tid & 63;
    const int lrow = lane & 15, kq = (lane >> 4) * 8;
    const int dh = (wave & 1) * 32;      // wave's d-half
    const int th = (wave >> 1) * 64;     // wave's t-half

    __shared__ __align__(16) float Ped[16 * 132];   // 8448 B epilogue staging

    const short* __restrict__ Ka = (const short*)(Kb  + (size_t)b * KLD * KLD);
    const short* __restrict__ Ta = (const short*)(Hbt + (size_t)b * TROWS * TPITCH);

    // A rows: clamp into the zero-padded tail (rows 257..287 of Kb are zeros)
    int ra0 = d0 + dh + lrow;        if (ra0 > KLD - 1) ra0 = KLD - 1;
    int ra1 = d0 + dh + 16 + lrow;   if (ra1 > KLD - 1) ra1 = KLD - 1;
    const short* __restrict__ pa0 = Ka + (size_t)ra0 * KLD + kq;
    const short* __restrict__ pa1 = Ka + (size_t)ra1 * KLD + kq;
    const short* __restrict__ pb0 = Ta + (size_t)(t0 + th +  0 + lrow) * TPITCH + kq;
    const short* __restrict__ pb1 = Ta + (size_t)(t0 + th + 16 + lrow) * TPITCH + kq;
    const short* __restrict__ pb2 = Ta + (size_t)(t0 + th + 32 + lrow) * TPITCH + kq;
    const short* __restrict__ pb3 = Ta + (size_t)(t0 + th + 48 + lrow) * TPITCH + kq;

    f32x4 acc[2][4] = {};

    bf16x8 a0 = *(const bf16x8*)pa0;
    bf16x8 a1 = *(const bf16x8*)pa1;
    bf16x8 b0 = *(const bf16x8*)pb0;
    bf16x8 b1 = *(const bf16x8*)pb1;
    bf16x8 b2 = *(const bf16x8*)pb2;
    bf16x8 b3 = *(const bf16x8*)pb3;

    for (int kt = 0; kt < 9; ++kt) {
        bf16x8 na0, na1, nb0, nb1, nb2, nb3;
        if (kt < 8) {
            const int off = (kt + 1) * 32;
            na0 = *(const bf16x8*)(pa0 + off);
            na1 = *(const bf16x8*)(pa1 + off);
            nb0 = *(const bf16x8*)(pb0 + off);
            nb1 = *(const bf16x8*)(pb1 + off);
            nb2 = *(const bf16x8*)(pb2 + off);
            nb3 = *(const bf16x8*)(pb3 + off);
        }
        acc[0][0] = __builtin_amdgcn_mfma_f32_16x16x32_bf16(a0, b0, acc[0][0], 0, 0, 0);
        acc[0][1] = __builtin_amdgcn_mfma_f32_16x16x32_bf16(a0, b1, acc[0][1], 0, 0, 0);
        acc[0][2] = __builtin_amdgcn_mfma_f32_16x16x32_bf16(a0, b2, acc[0][2], 0, 0, 0);
        acc[0][3] = __builtin_amdgcn_mfma_f32_16x16x32_bf16(a0, b3, acc[0][3], 0, 0, 0);
        acc[1][0] = __builtin_amdgcn_mfma_f32_16x16x32_bf16(a1, b0, acc[1][0], 0, 0, 0);
        acc[1][1] = __builtin_amdgcn_mfma_f32_16x16x32_bf16(a1, b1, acc[1][1], 0, 0, 0);
        acc[1][2] = __builtin_amdgcn_mfma_f32_16x16x32_bf16(a1, b2, acc[1][2], 0, 0, 0);
        acc[1][3] = __builtin_amdgcn_mfma_f32_16x16x32_bf16(a1, b3, acc[1][3], 0, 0, 0);
        if (kt < 8) {
            a0 = na0; a1 = na1;
            b0 = nb0; b1 = nb1; b2 = nb2; b3 = nb3;
        }
    }

    // epilogue: 4 chunks of 16 d-rows through LDS, lane-contiguous RMW
    const float* __restrict__ Hs = H + (size_t)b * DP * NP;
    float* __restrict__ Ob = Out + (size_t)b * DP * NP;
    const float inv_n = 1.0f / (float)NSEQ;
    const int ccol  = lane & 15;
    const int crow0 = (lane >> 4) * 4;
    const bool fullT = (t0 + 128 <= NP);   // false only for the x=16 block

#pragma unroll
    for (int c = 0; c < 4; ++c) {
        // waves whose d-half matches this chunk dump their i = (c&1) frags
        if ((wave & 1) == (c >> 1)) {
            const int i = c & 1;
#pragma unroll
            for (int j = 0; j < 4; ++j)
#pragma unroll
                for (int r = 0; r < 4; ++r)
                    Ped[(crow0 + r) * 132 + th + j * 16 + ccol] = acc[i][j][r];
        }
        __syncthreads();
        const int dchunk = d0 + c * 16;
        if (fullT) {
#pragma unroll
            for (int p = 0; p < 8; ++p) {
                const int lin = p * 256 + tid;
                const int row = lin >> 7;        // 0..15
                const int col = lin & 127;       // lane-contiguous
                const int gd = dchunk + row;
                if (gd < DP) {
                    const size_t idx = (size_t)gd * NP + t0 + col;
                    Ob[idx] = Hs[idx] + inv_n * Ped[row * 132 + col];
                }
            }
        } else {
#pragma unroll
            for (int p = 0; p < 8; ++p) {
                const int lin = p * 256 + tid;
                const int row = lin >> 7;
                const int col = lin & 127;
                const int gd = dchunk + row;
                const int gt = t0 + col;
                if (gd < DP && gt < NP) {
                    const size_t idx = (size_t)gd * NP + gt;
                    Ob[idx] = Hs[idx] + inv_n * Ped[row * 132 + col];
                }
            }
        }
        __syncthreads();
    }
}

extern "C" void kernel_launch(void* const* d_in, const int* in_sizes, int n_in,
                              void* d_out, int out_size, void* d_ws, size_t ws_size,
                              hipStream_t stream) {
    const float* H = (const float*)d_in[0];
    const float* P = (const float*)d_in[1];
    const float* Q = (const float*)d_in[2];
    float* out = (float*)d_out;

    __hip_bfloat16* Hb  = (__hip_bfloat16*)d_ws;                   // 16*320*2048
    __hip_bfloat16* Hbt = Hb  + (size_t)NB * HROWS * 2048;         // 16*2176*320
    __hip_bfloat16* G   = Hbt + (size_t)NB * TROWS * TPITCH;       // 16*288*288
    __hip_bfloat16* Pb  = G   + (size_t)NB * KLD * KLD;            // 288*288
    __hip_bfloat16* Qt  = Pb  + (size_t)KLD * KLD;                 // 288*288
    // W and Kb alias Hb's region (Hb is dead after gram_staged)
    __hip_bfloat16* W   = Hb;
    __hip_bfloat16* Kb  = Hb + (size_t)NB * KLD * KLD;

    conv_pq<<<dim3(5, 5, 2),   256, 0, stream>>>(P, Q, Pb, Qt);
    conv_h <<<dim3(34, 5, NB), 256, 0, stream>>>(H, Hb, Hbt);
    // G[b] = H-hat @ H-hat^T  (staged 64x64 tiles, in-block split-K x2)
    gram_staged<<<dim3(25, NB), 512, 0, stream>>>(Hb, G);
    // W[b] = P @ G[b]   (B-frags = G rows, valid by symmetry of G)
    mm_sk4<<<dim3(81, NB), 256, 0, stream>>>(Pb, G, W, 0, KLD * KLD);
    // Kb[b] = W[b] @ Q  (B-frags = Qt rows)
    mm_sk4<<<dim3(81, NB), 256, 0, stream>>>(W, Qt, Kb, KLD * KLD, 0);
    // out = H + (Kb @ H) / n
    attn_v3<<<dim3(17, 5, NB), 256, 0, stream>>>(Kb, Hbt, H, out);
}